// Round 8
// baseline (949.081 us; speedup 1.0000x reference)
//
#include <hip/hip_runtime.h>
#include <hip/hip_bf16.h>
#include <math.h>

#define N_NODES 50000
#define N_PADR  50048          // padded rows (= 391 * 128)
#define N_EDGES 800000
#define HIDDEN  128
#define POS_DIM 16
#define LAYERS  8
#define HEADS   8
#define HEAD_DIM 16
#define OUT_DIM 10
#define N_GRAPHS 128

using f32x4 = __attribute__((ext_vector_type(4))) float;
using half8 = __attribute__((ext_vector_type(8))) _Float16;
typedef _Float16 h2 __attribute__((ext_vector_type(2)));

#if defined(__has_builtin)
#if __has_builtin(__builtin_amdgcn_fdot2)
#define HAVE_FDOT2 1
#endif
#endif

__device__ __forceinline__ unsigned packh2(float a, float b) {   // 2xf32 -> packed f16 pair
    union { h2 h; unsigned u; } t;
    t.h = (h2){(_Float16)a, (_Float16)b};
    return t.u;
}
// s += dot(k8, q8) over 8 f16 pairs (one uint4 of packed f16)
__device__ __forceinline__ float dot8(uint4 k, const unsigned* q, float s) {
#if defined(HAVE_FDOT2)
    union { unsigned u; h2 h; } a, b;
    a.u = k.x; b.u = q[0]; s = __builtin_amdgcn_fdot2(a.h, b.h, s, false);
    a.u = k.y; b.u = q[1]; s = __builtin_amdgcn_fdot2(a.h, b.h, s, false);
    a.u = k.z; b.u = q[2]; s = __builtin_amdgcn_fdot2(a.h, b.h, s, false);
    a.u = k.w; b.u = q[3]; s = __builtin_amdgcn_fdot2(a.h, b.h, s, false);
    return s;
#else
    union { unsigned u; h2 h; } a, b;
#pragma unroll
    for (int j = 0; j < 4; ++j) {
        a.u = (&k.x)[j]; b.u = q[j];
        s += (float)a.h[0] * (float)b.h[0] + (float)a.h[1] * (float)b.h[1];
    }
    return s;
#endif
}

// ---------------- CSR row_ptr from sorted edge_row ----------------
__global__ void k_row_ptr(const int* __restrict__ row, int* __restrict__ row_ptr) {
    int e = blockIdx.x * blockDim.x + threadIdx.x;
    if (e >= N_EDGES) return;
    int cur  = row[e];
    int prev = (e == 0) ? -1 : row[e - 1];
    for (int r = prev + 1; r <= cur; ++r) row_ptr[r] = e;
    if (e == N_EDGES - 1) {
        for (int r = cur + 1; r <= N_NODES; ++r) row_ptr[r] = N_EDGES;
    }
}

// ---------------- W prep: coalesced LDS-tile transpose to f16 ----------------
// Wt[l3][n][k] = f16(W[l][k][n]); mat 0 (Wq) pre-scaled by 0.25 (exact).
// grid = 24 mats x 16 (32x32) tiles.
__global__ __launch_bounds__(256) void k_wprep(const float* __restrict__ Wq,
                                               const float* __restrict__ Wk,
                                               const float* __restrict__ Wv,
                                               unsigned short* __restrict__ Wt) {
    __shared__ float sT[32][33];
    const int l3 = blockIdx.x >> 4, tile = blockIdx.x & 15;
    const int layer = l3 / 3, mat = l3 % 3;
    const float* src = (mat == 0 ? Wq : mat == 1 ? Wk : Wv) + (size_t)layer * HIDDEN * HIDDEN;
    const float scl = (mat == 0) ? 0.25f : 1.0f;
    unsigned short* dh = Wt + (size_t)l3 * HIDDEN * HIDDEN;
    const int k0 = (tile >> 2) * 32, n0 = (tile & 3) * 32;
    const int tx = threadIdx.x & 31, ty = threadIdx.x >> 5;   // 32 x 8
#pragma unroll
    for (int i = 0; i < 4; ++i)
        sT[ty + i * 8][tx] = src[(size_t)(k0 + ty + i * 8) * HIDDEN + n0 + tx];
    __syncthreads();
#pragma unroll
    for (int i = 0; i < 4; ++i) {
        const int nr = ty + i * 8;
        union { h2 h; unsigned u; } t;
        t.h = (h2){(_Float16)(sT[tx][nr] * scl), (_Float16)0.f};
        dh[(size_t)(n0 + nr) * HIDDEN + k0 + tx] = (unsigned short)(t.u & 0xffffu);
    }
}

// ---------------- h0 = pos_enc @ Wpos + bpos (writes f16) ----------------
__global__ __launch_bounds__(256) void k_pos(const float* __restrict__ pos,
                                             const float* __restrict__ Wpos,
                                             const float* __restrict__ bpos,
                                             unsigned short* __restrict__ h) {
    __shared__ float sW[POS_DIM][HIDDEN];
    __shared__ float sb[HIDDEN];
    int t = threadIdx.x;
    for (int i = t; i < POS_DIM * HIDDEN; i += 256) sW[i / HIDDEN][i % HIDDEN] = Wpos[i];
    if (t < HIDDEN) sb[t] = bpos[t];
    __syncthreads();
    int n = blockIdx.x * 2 + (t >> 7);
    int j = t & 127;
    if (n >= N_NODES) return;
    float acc = sb[j];
#pragma unroll
    for (int q = 0; q < POS_DIM; ++q) acc += pos[n * POS_DIM + q] * sW[q][j];
    union { h2 h; unsigned u; } v;
    v.h = (h2){(_Float16)acc, (_Float16)0.f};
    h[(size_t)n * HIDDEN + j] = (unsigned short)(v.u & 0xffffu);
}

// ---------------- fused QKV: 128x128 tile, 8 waves, B dbuf across mats ------
// 391 blocks x 512 threads. A (128x128 f16 = 32 KB) staged via global_load_lds
// width-16 with XOR swizzle (chunk ^ row&15) pre-applied on the global source,
// same XOR on ds_read -> bank-uniform. Wave w owns col-block w (cols 16w..16w+15)
// for all 128 rows; its 4 B-fragments per mat are double-buffered across the
// mat loop (next mat's loads issue before current mat's MFMAs).
// acc = mfma(B_frag, A_frag, acc): lane(c=lane>>4, r=lane&15) holds
// rows m0+mb*16+r, cols w*16+c*4..+3 (contiguous) -> uint2 stores.
// Outputs: Q packed-f16 pairs [row][64 u32]; K/V f16 interleaved [row][256]
// (K at +0, V at +128).
__global__ __launch_bounds__(512, 4) void k_qkv(const unsigned short* __restrict__ h,
                                                const unsigned short* __restrict__ Wt,
                                                const float* __restrict__ bq,
                                                const float* __restrict__ bk,
                                                const float* __restrict__ bv,
                                                unsigned* __restrict__ Qh,
                                                unsigned short* __restrict__ KV,
                                                int layer) {
    __shared__ unsigned char sA[128 * 256];   // 128 rows x 256 B (f16)

    const int t = threadIdx.x;
    const int w = t >> 6, lane = t & 63;
    const int c = lane >> 4, r = lane & 15;
    const int m0 = blockIdx.x * 128;

    // ---- stage A tile: 4 async rounds x 512 lanes x 16 B = 32 KB ----
    {
        const char* src = (const char*)h + (size_t)m0 * 256;
#pragma unroll
        for (int i = 0; i < 4; ++i) {
            const int s   = i * 512 + t;
            const int row = s >> 4;
            const int ch  = s & 15;
            const char* g = src + row * 256 + ((ch ^ (row & 15)) << 4);
            char* l = (char*)&sA[s << 4];
            __builtin_amdgcn_global_load_lds(
                (const __attribute__((address_space(1))) unsigned int*)g,
                (__attribute__((address_space(3))) unsigned int*)l, 16, 0, 0);
        }
    }

    // swizzled A chunk offsets are mb-invariant: (mb*16+r)&15 == r
    int aoff[4];
#pragma unroll
    for (int kc = 0; kc < 4; ++kc) aoff[kc] = ((((kc << 2) + c) ^ r) << 4);

    const size_t wrow = (size_t)(w * 16 + r) * HIDDEN + c * 8;
    const unsigned short* wt0 = Wt + (size_t)(layer * 3) * (HIDDEN * HIDDEN);

    half8 B[2][4];
#pragma unroll
    for (int kc = 0; kc < 4; ++kc)
        B[0][kc] = *(const half8*)&wt0[wrow + kc * 32];

    __syncthreads();

#pragma unroll
    for (int mat = 0; mat < 3; ++mat) {
        const int cur = mat & 1;
        // prefetch next mat's B fragments (hide L2 latency under MFMAs)
        if (mat < 2) {
            const unsigned short* wtn = Wt + (size_t)(layer * 3 + mat + 1) * (HIDDEN * HIDDEN);
#pragma unroll
            for (int kc = 0; kc < 4; ++kc)
                B[cur ^ 1][kc] = *(const half8*)&wtn[wrow + kc * 32];
        }

        f32x4 acc[8];
#pragma unroll
        for (int mb = 0; mb < 8; ++mb) acc[mb] = (f32x4){0.f, 0.f, 0.f, 0.f};

#pragma unroll
        for (int mb = 0; mb < 8; ++mb) {
            const int abase = (mb * 16 + r) * 256;
            half8 a0 = *(const half8*)&sA[abase + aoff[0]];
            half8 a1 = *(const half8*)&sA[abase + aoff[1]];
            half8 a2 = *(const half8*)&sA[abase + aoff[2]];
            half8 a3 = *(const half8*)&sA[abase + aoff[3]];
            acc[mb] = __builtin_amdgcn_mfma_f32_16x16x32_f16(B[cur][0], a0, acc[mb], 0, 0, 0);
            acc[mb] = __builtin_amdgcn_mfma_f32_16x16x32_f16(B[cur][1], a1, acc[mb], 0, 0, 0);
            acc[mb] = __builtin_amdgcn_mfma_f32_16x16x32_f16(B[cur][2], a2, acc[mb], 0, 0, 0);
            acc[mb] = __builtin_amdgcn_mfma_f32_16x16x32_f16(B[cur][3], a3, acc[mb], 0, 0, 0);
        }

        // epilogue for this mat
        const float* bias = (mat == 0 ? bq : mat == 1 ? bk : bv) + layer * HIDDEN;
        float4 b4 = *(const float4*)&bias[w * 16 + c * 4];
        if (mat == 0) { b4.x *= 0.25f; b4.y *= 0.25f; b4.z *= 0.25f; b4.w *= 0.25f; }
#pragma unroll
        for (int mb = 0; mb < 8; ++mb) {
            const size_t m = m0 + mb * 16 + r;
            uint2 o = make_uint2(packh2(acc[mb][0] + b4.x, acc[mb][1] + b4.y),
                                 packh2(acc[mb][2] + b4.z, acc[mb][3] + b4.w));
            if (mat == 0) {
                *(uint2*)&Qh[m * 64 + w * 8 + c * 2] = o;
            } else {
                unsigned short* dst = KV + m * 256 + (mat == 2 ? 128 : 0) + w * 16 + c * 4;
                *(uint2*)dst = o;
            }
        }
    }
}

// ---------------- per-node edge softmax + aggregation ----------------
// One wave / node; 8 groups x 8 lanes; group g owns edges start+g, start+g+8...
// Lane covers 16 dims = one head -> score lane-local via f16 dot2.
// Flat-exp softmax (scores ~N(0,1); no overflow possible).
// V accumulated via p * (float)f16 elementwise -> v_fma_mix (no unpack pass).
// K,V f16 interleaved (one 512B region per edge). Depth-2 pipeline.
__global__ __launch_bounds__(256) void k_attn(const unsigned* __restrict__ Qh,
                                              const unsigned short* __restrict__ KV,
                                              const int* __restrict__ col,
                                              const int* __restrict__ row_ptr,
                                              unsigned short* __restrict__ hout) {
    int wid  = (blockIdx.x * blockDim.x + threadIdx.x) >> 6;
    int lane = threadIdx.x & 63;
    if (wid >= N_NODES) return;
    const int g  = lane >> 3;
    const int lg = lane & 7;
    const int d0 = lg * 16;
    const int start = row_ptr[wid];
    const int end   = row_ptr[wid + 1];

    unsigned q2[8];
    {
        uint4 qa = *(const uint4*)&Qh[(size_t)wid * 64 + lg * 8];
        uint4 qb = *(const uint4*)&Qh[(size_t)wid * 64 + lg * 8 + 4];
        q2[0] = qa.x; q2[1] = qa.y; q2[2] = qa.z; q2[3] = qa.w;
        q2[4] = qb.x; q2[5] = qb.y; q2[6] = qb.z; q2[7] = qb.w;
    }

    float dsum = 0.f;
    float acc[16];
#pragma unroll
    for (int i = 0; i < 16; ++i) acc[i] = 0.f;

    int e = start + g;
    int c = (e < end) ? col[e] : -1;
    uint4 kA, kB, vA, vB;
    if (c >= 0) {
        const uint4* kp = (const uint4*)(KV + (size_t)c * 256 + d0);
        const uint4* vp = (const uint4*)(KV + (size_t)c * 256 + 128 + d0);
        kA = kp[0]; kB = kp[1]; vA = vp[0]; vB = vp[1];
    }
    while (c >= 0) {
        int en = e + 8;
        int cn = (en < end) ? col[en] : -1;
        uint4 nkA, nkB, nvA, nvB;
        if (cn >= 0) {
            const uint4* kp = (const uint4*)(KV + (size_t)cn * 256 + d0);
            const uint4* vp = (const uint4*)(KV + (size_t)cn * 256 + 128 + d0);
            nkA = kp[0]; nkB = kp[1]; nvA = vp[0]; nvB = vp[1];
        }
        float s = dot8(kA, q2, 0.f);
        s = dot8(kB, q2 + 4, s);
        float p = __expf(s);
        dsum += p;
        union { unsigned u; h2 h; } tv;
#pragma unroll
        for (int j = 0; j < 4; ++j) {
            tv.u = (&vA.x)[j];
            acc[2 * j]     += p * (float)tv.h[0];
            acc[2 * j + 1] += p * (float)tv.h[1];
        }
#pragma unroll
        for (int j = 0; j < 4; ++j) {
            tv.u = (&vB.x)[j];
            acc[8 + 2 * j]     += p * (float)tv.h[0];
            acc[8 + 2 * j + 1] += p * (float)tv.h[1];
        }
        e = en; c = cn;
        kA = nkA; kB = nkB; vA = nvA; vB = nvB;
    }
    // merge the 8 groups: plain sums
#pragma unroll
    for (int off = 8; off < 64; off <<= 1) {
        dsum += __shfl_xor(dsum, off);
#pragma unroll
        for (int i = 0; i < 16; ++i) acc[i] += __shfl_xor(acc[i], off);
    }
    if (g == 0) {
        float inv = (end > start) ? 1.f / fmaxf(dsum, 1e-30f) : 0.f;
        unsigned hw[8];
#pragma unroll
        for (int j = 0; j < 8; ++j)
            hw[j] = packh2(acc[2 * j] * inv, acc[2 * j + 1] * inv);
        uint4* ph = (uint4*)(hout + (size_t)wid * HIDDEN + d0);
        ph[0] = make_uint4(hw[0], hw[1], hw[2], hw[3]);
        ph[1] = make_uint4(hw[4], hw[5], hw[6], hw[7]);
    }
}

// ---------------- graph pooling: sorted-gid run accumulation ----------------
__global__ __launch_bounds__(256) void k_pool(const unsigned short* __restrict__ h,
                                              const int* __restrict__ gid,
                                              float* __restrict__ pooled) {
    const int ch   = threadIdx.x & 127;
    const int half = threadIdx.x >> 7;
    const int n0   = blockIdx.x * 128 + half * 64;
    float run = 0.f;
    int   rg  = -1;
    for (int i = 0; i < 64; ++i) {
        int n = n0 + i;
        if (n >= N_NODES) break;
        int g = gid[n];
        if (g != rg) {
            if (rg >= 0) atomicAdd(&pooled[rg * HIDDEN + ch], run);
            rg = g; run = 0.f;
        }
        union { unsigned u; h2 hh; } v;
        v.u = (unsigned)h[(size_t)n * HIDDEN + ch];
        run += (float)v.hh[0];
    }
    if (rg >= 0) atomicAdd(&pooled[rg * HIDDEN + ch], run);
}

// ---------------- pred: out = pooled @ Wpred + bpred ----------------
__global__ void k_pred(const float* __restrict__ pooled, const float* __restrict__ Wp,
                       const float* __restrict__ bp, float* __restrict__ out) {
    int idx = blockIdx.x * blockDim.x + threadIdx.x;
    if (idx >= N_GRAPHS * OUT_DIM) return;
    int g = idx / OUT_DIM, o = idx % OUT_DIM;
    float acc = bp[o];
#pragma unroll 4
    for (int j = 0; j < HIDDEN; ++j) acc += pooled[g * HIDDEN + j] * Wp[j * OUT_DIM + o];
    out[idx] = acc;
}

extern "C" void kernel_launch(void* const* d_in, const int* in_sizes, int n_in,
                              void* d_out, int out_size, void* d_ws, size_t ws_size,
                              hipStream_t stream) {
    // d_in[0] = X : UNUSED by the reference
    const float* pos   = (const float*)d_in[1];
    const int*   erow  = (const int*)d_in[2];
    const int*   ecol  = (const int*)d_in[3];
    const int*   gid   = (const int*)d_in[4];
    const float* Wpos  = (const float*)d_in[5];
    const float* bpos  = (const float*)d_in[6];
    const float* Wq    = (const float*)d_in[7];
    const float* bq    = (const float*)d_in[8];
    const float* Wk    = (const float*)d_in[9];
    const float* bk    = (const float*)d_in[10];
    const float* Wv    = (const float*)d_in[11];
    const float* bv    = (const float*)d_in[12];
    const float* Wpred = (const float*)d_in[13];
    const float* bpred = (const float*)d_in[14];
    float* out = (float*)d_out;

    char* base = (char*)d_ws;
    size_t off = 0;
    auto alloc = [&](size_t bytes) {
        void* r = base + off;
        off += (bytes + 255) & ~(size_t)255;
        return r;
    };
    unsigned short* h    = (unsigned short*)alloc((size_t)N_PADR * HIDDEN * 2);
    unsigned*       Qh   = (unsigned*)alloc((size_t)N_PADR * 64 * 4);
    unsigned short* KVb  = (unsigned short*)alloc((size_t)N_PADR * 256 * 2);
    unsigned short* Wt   = (unsigned short*)alloc((size_t)LAYERS * 3 * HIDDEN * HIDDEN * 2);
    int*   rowp   = (int*)alloc((size_t)(N_NODES + 1) * 4);
    float* pooled = (float*)alloc((size_t)N_GRAPHS * HIDDEN * 4);

    k_row_ptr<<<(N_EDGES + 255) / 256, 256, 0, stream>>>(erow, rowp);
    k_wprep<<<LAYERS * 3 * 16, 256, 0, stream>>>(Wq, Wk, Wv, Wt);
    k_pos<<<N_NODES / 2, 256, 0, stream>>>(pos, Wpos, bpos, h);

    for (int l = 0; l < LAYERS; ++l) {
        k_qkv<<<N_PADR / 128, 512, 0, stream>>>(h, Wt, bq, bk, bv, Qh, KVb, l);
        k_attn<<<(N_NODES * 64 + 255) / 256, 256, 0, stream>>>(Qh, KVb, ecol, rowp, h);
    }

    hipMemsetAsync(pooled, 0, N_GRAPHS * HIDDEN * 4, stream);
    k_pool<<<(N_NODES + 127) / 128, 256, 0, stream>>>(h, gid, pooled);
    k_pred<<<(N_GRAPHS * OUT_DIM + 255) / 256, 256, 0, stream>>>(pooled, Wpred, bpred, out);
}

// Round 9
// 848.032 us; speedup vs baseline: 1.1192x; 1.1192x over previous
//
#include <hip/hip_runtime.h>
#include <hip/hip_bf16.h>
#include <math.h>

#define N_NODES 50000
#define N_PADR  50048          // padded rows (= 782 * 64)
#define N_EDGES 800000
#define HIDDEN  128
#define POS_DIM 16
#define LAYERS  8
#define HEADS   8
#define HEAD_DIM 16
#define OUT_DIM 10
#define N_GRAPHS 128

using f32x4 = __attribute__((ext_vector_type(4))) float;
using half8 = __attribute__((ext_vector_type(8))) _Float16;
typedef _Float16 h2 __attribute__((ext_vector_type(2)));

#if defined(__has_builtin)
#if __has_builtin(__builtin_amdgcn_fdot2)
#define HAVE_FDOT2 1
#endif
#endif

__device__ __forceinline__ unsigned packh2(float a, float b) {   // 2xf32 -> packed f16 pair
    union { h2 h; unsigned u; } t;
    t.h = (h2){(_Float16)a, (_Float16)b};
    return t.u;
}
// s += dot(k8, q8) over 8 f16 pairs (one uint4 of packed f16)
__device__ __forceinline__ float dot8(uint4 k, const unsigned* q, float s) {
#if defined(HAVE_FDOT2)
    union { unsigned u; h2 h; } a, b;
    a.u = k.x; b.u = q[0]; s = __builtin_amdgcn_fdot2(a.h, b.h, s, false);
    a.u = k.y; b.u = q[1]; s = __builtin_amdgcn_fdot2(a.h, b.h, s, false);
    a.u = k.z; b.u = q[2]; s = __builtin_amdgcn_fdot2(a.h, b.h, s, false);
    a.u = k.w; b.u = q[3]; s = __builtin_amdgcn_fdot2(a.h, b.h, s, false);
    return s;
#else
    union { unsigned u; h2 h; } a, b;
#pragma unroll
    for (int j = 0; j < 4; ++j) {
        a.u = (&k.x)[j]; b.u = q[j];
        s += (float)a.h[0] * (float)b.h[0] + (float)a.h[1] * (float)b.h[1];
    }
    return s;
#endif
}

// ---------------- CSR row_ptr from sorted edge_row ----------------
__global__ void k_row_ptr(const int* __restrict__ row, int* __restrict__ row_ptr) {
    int e = blockIdx.x * blockDim.x + threadIdx.x;
    if (e >= N_EDGES) return;
    int cur  = row[e];
    int prev = (e == 0) ? -1 : row[e - 1];
    for (int r = prev + 1; r <= cur; ++r) row_ptr[r] = e;
    if (e == N_EDGES - 1) {
        for (int r = cur + 1; r <= N_NODES; ++r) row_ptr[r] = N_EDGES;
    }
}

// ---------------- W prep: coalesced LDS-tile transpose to f16 ----------------
// Wt[l3][n][k] = f16(W[l][k][n]); mat 0 (Wq) pre-scaled by 0.25 (exact).
// grid = 24 mats x 16 (32x32) tiles.
__global__ __launch_bounds__(256) void k_wprep(const float* __restrict__ Wq,
                                               const float* __restrict__ Wk,
                                               const float* __restrict__ Wv,
                                               unsigned short* __restrict__ Wt) {
    __shared__ float sT[32][33];
    const int l3 = blockIdx.x >> 4, tile = blockIdx.x & 15;
    const int layer = l3 / 3, mat = l3 % 3;
    const float* src = (mat == 0 ? Wq : mat == 1 ? Wk : Wv) + (size_t)layer * HIDDEN * HIDDEN;
    const float scl = (mat == 0) ? 0.25f : 1.0f;
    unsigned short* dh = Wt + (size_t)l3 * HIDDEN * HIDDEN;
    const int k0 = (tile >> 2) * 32, n0 = (tile & 3) * 32;
    const int tx = threadIdx.x & 31, ty = threadIdx.x >> 5;   // 32 x 8
#pragma unroll
    for (int i = 0; i < 4; ++i)
        sT[ty + i * 8][tx] = src[(size_t)(k0 + ty + i * 8) * HIDDEN + n0 + tx];
    __syncthreads();
#pragma unroll
    for (int i = 0; i < 4; ++i) {
        const int nr = ty + i * 8;
        union { h2 h; unsigned u; } t;
        t.h = (h2){(_Float16)(sT[tx][nr] * scl), (_Float16)0.f};
        dh[(size_t)(n0 + nr) * HIDDEN + k0 + tx] = (unsigned short)(t.u & 0xffffu);
    }
}

// ---------------- h0 = pos_enc @ Wpos + bpos (writes f16) ----------------
__global__ __launch_bounds__(256) void k_pos(const float* __restrict__ pos,
                                             const float* __restrict__ Wpos,
                                             const float* __restrict__ bpos,
                                             unsigned short* __restrict__ h) {
    __shared__ float sW[POS_DIM][HIDDEN];
    __shared__ float sb[HIDDEN];
    int t = threadIdx.x;
    for (int i = t; i < POS_DIM * HIDDEN; i += 256) sW[i / HIDDEN][i % HIDDEN] = Wpos[i];
    if (t < HIDDEN) sb[t] = bpos[t];
    __syncthreads();
    int n = blockIdx.x * 2 + (t >> 7);
    int j = t & 127;
    if (n >= N_NODES) return;
    float acc = sb[j];
#pragma unroll
    for (int q = 0; q < POS_DIM; ++q) acc += pos[n * POS_DIM + q] * sW[q][j];
    union { h2 h; unsigned u; } v;
    v.h = (h2){(_Float16)acc, (_Float16)0.f};
    h[(size_t)n * HIDDEN + j] = (unsigned short)(v.u & 0xffffu);
}

// ---------------- QKV: one mat per block, max TLP ----------------
// Grid (782, 3): blockIdx.x = 64-row tile, blockIdx.y = mat (Q/K/V).
// 256 threads = 4 waves; wave w owns col-blocks 2w, 2w+1.
// A (64x128 f16 = 16 KB) staged via global_load_lds width-16 with XOR swizzle
// (chunk ^ row&15) pre-applied on the global source, same XOR on ds_read.
// B fragments (8 x 16B, L2-hot) are issued BEFORE the barrier so they fly
// concurrently with the stage. acc = mfma(B, A, acc): lane(c,r) holds rows
// m0+mb*16+r, cols (2w+nbp)*16+c*4..+3 -> uint2 stores.
// Outputs: Q packed-f16 pairs [row][64 u32]; K/V f16 interleaved [row][256]
// (K at +0, V at +128).
__global__ __launch_bounds__(256) void k_qkv(const unsigned short* __restrict__ h,
                                             const unsigned short* __restrict__ Wt,
                                             const float* __restrict__ bq,
                                             const float* __restrict__ bk,
                                             const float* __restrict__ bv,
                                             unsigned* __restrict__ Qh,
                                             unsigned short* __restrict__ KV,
                                             int layer) {
    __shared__ unsigned char sA[64 * 256];   // 64 rows x 256 B (f16)

    const int t = threadIdx.x;
    const int w = t >> 6, lane = t & 63;
    const int c = lane >> 4, r = lane & 15;
    const int m0 = blockIdx.x * 64;
    const int mat = blockIdx.y;

    // ---- stage A tile: 4 async rounds x 256 lanes x 16 B = 16 KB ----
    {
        const char* src = (const char*)h + (size_t)m0 * 256;
#pragma unroll
        for (int i = 0; i < 4; ++i) {
            const int s   = i * 256 + t;                  // 16B slot
            const int row = s >> 4;
            const int ch  = s & 15;
            const char* g = src + row * 256 + ((ch ^ (row & 15)) << 4);
            char* l = (char*)&sA[(i * 256 + w * 64) << 4];  // wave-uniform base
            __builtin_amdgcn_global_load_lds(
                (const __attribute__((address_space(1))) unsigned int*)g,
                (__attribute__((address_space(3))) unsigned int*)l, 16, 0, 0);
        }
    }

    // ---- B fragments: issued now, in flight during the stage ----
    const unsigned short* wt = Wt + (size_t)(layer * 3 + mat) * (HIDDEN * HIDDEN);
    const int nbase = w * 2;
    half8 B[2][4];
#pragma unroll
    for (int nbp = 0; nbp < 2; ++nbp)
#pragma unroll
        for (int kc = 0; kc < 4; ++kc)
            B[nbp][kc] = *(const half8*)&wt[(size_t)((nbase + nbp) * 16 + r) * HIDDEN + kc * 32 + c * 8];

    __syncthreads();

    f32x4 acc[4][2];
#pragma unroll
    for (int mb = 0; mb < 4; ++mb)
#pragma unroll
        for (int nbp = 0; nbp < 2; ++nbp)
            acc[mb][nbp] = (f32x4){0.f, 0.f, 0.f, 0.f};

#pragma unroll
    for (int mb = 0; mb < 4; ++mb) {
        const int abase = (mb * 16 + r) * 256;
        half8 a[4];
#pragma unroll
        for (int kc = 0; kc < 4; ++kc)
            a[kc] = *(const half8*)&sA[abase + ((((kc << 2) + c) ^ r) << 4)];
#pragma unroll
        for (int nbp = 0; nbp < 2; ++nbp)
#pragma unroll
            for (int kc = 0; kc < 4; ++kc)
                acc[mb][nbp] = __builtin_amdgcn_mfma_f32_16x16x32_f16(B[nbp][kc], a[kc], acc[mb][nbp], 0, 0, 0);
    }

    // ---- epilogue ----
    const float* bias = (mat == 0 ? bq : mat == 1 ? bk : bv) + layer * HIDDEN;
#pragma unroll
    for (int mb = 0; mb < 4; ++mb) {
        const size_t m = m0 + mb * 16 + r;
#pragma unroll
        for (int nbp = 0; nbp < 2; ++nbp) {
            const int n0 = (nbase + nbp) * 16 + c * 4;
            float4 b4 = *(const float4*)&bias[n0];
            float v0, v1, v2, v3;
            if (mat == 0) {          // Wq pre-scaled by 0.25; scale bias here
                v0 = acc[mb][nbp][0] + b4.x * 0.25f;
                v1 = acc[mb][nbp][1] + b4.y * 0.25f;
                v2 = acc[mb][nbp][2] + b4.z * 0.25f;
                v3 = acc[mb][nbp][3] + b4.w * 0.25f;
            } else {
                v0 = acc[mb][nbp][0] + b4.x;
                v1 = acc[mb][nbp][1] + b4.y;
                v2 = acc[mb][nbp][2] + b4.z;
                v3 = acc[mb][nbp][3] + b4.w;
            }
            uint2 o = make_uint2(packh2(v0, v1), packh2(v2, v3));
            if (mat == 0) {
                *(uint2*)&Qh[m * 64 + (n0 >> 1)] = o;
            } else {
                unsigned short* dst = KV + m * 256 + (mat == 2 ? 128 : 0) + n0;
                *(uint2*)dst = o;
            }
        }
    }
}

// ---------------- per-node edge softmax + aggregation ----------------
// One wave / node; 8 groups x 8 lanes; group g owns edges start+g, start+g+8...
// Lane covers 16 dims = one head -> score lane-local via f16 dot2.
// Flat-exp softmax (scores ~N(0,1); no overflow possible).
// V accumulated via p * (float)f16 elementwise -> v_fma_mix (no unpack pass).
// K,V f16 interleaved (one 512B region per edge). Depth-2 pipeline.
__global__ __launch_bounds__(256) void k_attn(const unsigned* __restrict__ Qh,
                                              const unsigned short* __restrict__ KV,
                                              const int* __restrict__ col,
                                              const int* __restrict__ row_ptr,
                                              unsigned short* __restrict__ hout) {
    int wid  = (blockIdx.x * blockDim.x + threadIdx.x) >> 6;
    int lane = threadIdx.x & 63;
    if (wid >= N_NODES) return;
    const int g  = lane >> 3;
    const int lg = lane & 7;
    const int d0 = lg * 16;
    const int start = row_ptr[wid];
    const int end   = row_ptr[wid + 1];

    unsigned q2[8];
    {
        uint4 qa = *(const uint4*)&Qh[(size_t)wid * 64 + lg * 8];
        uint4 qb = *(const uint4*)&Qh[(size_t)wid * 64 + lg * 8 + 4];
        q2[0] = qa.x; q2[1] = qa.y; q2[2] = qa.z; q2[3] = qa.w;
        q2[4] = qb.x; q2[5] = qb.y; q2[6] = qb.z; q2[7] = qb.w;
    }

    float dsum = 0.f;
    float acc[16];
#pragma unroll
    for (int i = 0; i < 16; ++i) acc[i] = 0.f;

    int e = start + g;
    int c = (e < end) ? col[e] : -1;
    uint4 kA, kB, vA, vB;
    if (c >= 0) {
        const uint4* kp = (const uint4*)(KV + (size_t)c * 256 + d0);
        const uint4* vp = (const uint4*)(KV + (size_t)c * 256 + 128 + d0);
        kA = kp[0]; kB = kp[1]; vA = vp[0]; vB = vp[1];
    }
    while (c >= 0) {
        int en = e + 8;
        int cn = (en < end) ? col[en] : -1;
        uint4 nkA, nkB, nvA, nvB;
        if (cn >= 0) {
            const uint4* kp = (const uint4*)(KV + (size_t)cn * 256 + d0);
            const uint4* vp = (const uint4*)(KV + (size_t)cn * 256 + 128 + d0);
            nkA = kp[0]; nkB = kp[1]; nvA = vp[0]; nvB = vp[1];
        }
        float s = dot8(kA, q2, 0.f);
        s = dot8(kB, q2 + 4, s);
        float p = __expf(s);
        dsum += p;
        union { unsigned u; h2 h; } tv;
#pragma unroll
        for (int j = 0; j < 4; ++j) {
            tv.u = (&vA.x)[j];
            acc[2 * j]     += p * (float)tv.h[0];
            acc[2 * j + 1] += p * (float)tv.h[1];
        }
#pragma unroll
        for (int j = 0; j < 4; ++j) {
            tv.u = (&vB.x)[j];
            acc[8 + 2 * j]     += p * (float)tv.h[0];
            acc[8 + 2 * j + 1] += p * (float)tv.h[1];
        }
        e = en; c = cn;
        kA = nkA; kB = nkB; vA = nvA; vB = nvB;
    }
    // merge the 8 groups: plain sums
#pragma unroll
    for (int off = 8; off < 64; off <<= 1) {
        dsum += __shfl_xor(dsum, off);
#pragma unroll
        for (int i = 0; i < 16; ++i) acc[i] += __shfl_xor(acc[i], off);
    }
    if (g == 0) {
        float inv = (end > start) ? 1.f / fmaxf(dsum, 1e-30f) : 0.f;
        unsigned hw[8];
#pragma unroll
        for (int j = 0; j < 8; ++j)
            hw[j] = packh2(acc[2 * j] * inv, acc[2 * j + 1] * inv);
        uint4* ph = (uint4*)(hout + (size_t)wid * HIDDEN + d0);
        ph[0] = make_uint4(hw[0], hw[1], hw[2], hw[3]);
        ph[1] = make_uint4(hw[4], hw[5], hw[6], hw[7]);
    }
}

// ---------------- graph pooling: sorted-gid run accumulation ----------------
__global__ __launch_bounds__(256) void k_pool(const unsigned short* __restrict__ h,
                                              const int* __restrict__ gid,
                                              float* __restrict__ pooled) {
    const int ch   = threadIdx.x & 127;
    const int half = threadIdx.x >> 7;
    const int n0   = blockIdx.x * 128 + half * 64;
    float run = 0.f;
    int   rg  = -1;
    for (int i = 0; i < 64; ++i) {
        int n = n0 + i;
        if (n >= N_NODES) break;
        int g = gid[n];
        if (g != rg) {
            if (rg >= 0) atomicAdd(&pooled[rg * HIDDEN + ch], run);
            rg = g; run = 0.f;
        }
        union { unsigned u; h2 hh; } v;
        v.u = (unsigned)h[(size_t)n * HIDDEN + ch];
        run += (float)v.hh[0];
    }
    if (rg >= 0) atomicAdd(&pooled[rg * HIDDEN + ch], run);
}

// ---------------- pred: out = pooled @ Wpred + bpred ----------------
__global__ void k_pred(const float* __restrict__ pooled, const float* __restrict__ Wp,
                       const float* __restrict__ bp, float* __restrict__ out) {
    int idx = blockIdx.x * blockDim.x + threadIdx.x;
    if (idx >= N_GRAPHS * OUT_DIM) return;
    int g = idx / OUT_DIM, o = idx % OUT_DIM;
    float acc = bp[o];
#pragma unroll 4
    for (int j = 0; j < HIDDEN; ++j) acc += pooled[g * HIDDEN + j] * Wp[j * OUT_DIM + o];
    out[idx] = acc;
}

extern "C" void kernel_launch(void* const* d_in, const int* in_sizes, int n_in,
                              void* d_out, int out_size, void* d_ws, size_t ws_size,
                              hipStream_t stream) {
    // d_in[0] = X : UNUSED by the reference
    const float* pos   = (const float*)d_in[1];
    const int*   erow  = (const int*)d_in[2];
    const int*   ecol  = (const int*)d_in[3];
    const int*   gid   = (const int*)d_in[4];
    const float* Wpos  = (const float*)d_in[5];
    const float* bpos  = (const float*)d_in[6];
    const float* Wq    = (const float*)d_in[7];
    const float* bq    = (const float*)d_in[8];
    const float* Wk    = (const float*)d_in[9];
    const float* bk    = (const float*)d_in[10];
    const float* Wv    = (const float*)d_in[11];
    const float* bv    = (const float*)d_in[12];
    const float* Wpred = (const float*)d_in[13];
    const float* bpred = (const float*)d_in[14];
    float* out = (float*)d_out;

    char* base = (char*)d_ws;
    size_t off = 0;
    auto alloc = [&](size_t bytes) {
        void* r = base + off;
        off += (bytes + 255) & ~(size_t)255;
        return r;
    };
    unsigned short* h    = (unsigned short*)alloc((size_t)N_PADR * HIDDEN * 2);
    unsigned*       Qh   = (unsigned*)alloc((size_t)N_PADR * 64 * 4);
    unsigned short* KVb  = (unsigned short*)alloc((size_t)N_PADR * 256 * 2);
    unsigned short* Wt   = (unsigned short*)alloc((size_t)LAYERS * 3 * HIDDEN * HIDDEN * 2);
    int*   rowp   = (int*)alloc((size_t)(N_NODES + 1) * 4);
    float* pooled = (float*)alloc((size_t)N_GRAPHS * HIDDEN * 4);

    k_row_ptr<<<(N_EDGES + 255) / 256, 256, 0, stream>>>(erow, rowp);
    k_wprep<<<LAYERS * 3 * 16, 256, 0, stream>>>(Wq, Wk, Wv, Wt);
    k_pos<<<N_NODES / 2, 256, 0, stream>>>(pos, Wpos, bpos, h);

    for (int l = 0; l < LAYERS; ++l) {
        dim3 g(N_PADR / 64, 3, 1);
        k_qkv<<<g, 256, 0, stream>>>(h, Wt, bq, bk, bv, Qh, KVb, l);
        k_attn<<<(N_NODES * 64 + 255) / 256, 256, 0, stream>>>(Qh, KVb, ecol, rowp, h);
    }

    hipMemsetAsync(pooled, 0, N_GRAPHS * HIDDEN * 4, stream);
    k_pool<<<(N_NODES + 127) / 128, 256, 0, stream>>>(h, gid, pooled);
    k_pred<<<(N_GRAPHS * OUT_DIM + 255) / 256, 256, 0, stream>>>(pooled, Wpred, bpred, out);
}